// Round 7
// baseline (1193.925 us; speedup 1.0000x reference)
//
#include <hip/hip_runtime.h>
#include <hip/hip_fp16.h>
#include <hip/hip_fp8.h>
#include <cstdint>

// B=64, T=512, F=1024, U=256, G=4U=1024
#define BB 64
#define TT 512
#define FF 1024
#define UU 256
#define GG 1024

typedef _Float16 f16x8 __attribute__((ext_vector_type(8)));
typedef float f32x4 __attribute__((ext_vector_type(4)));

typedef union { uint2 u; long long l; } pk8;   // 8 fp8 = one MFMA operand (2 VGPRs)

__device__ __forceinline__ float sigmf_(float x) { return 1.f / (1.f + __expf(-x)); }
__device__ __forceinline__ float tanhf_(float x) { return 1.f - 2.f / (1.f + __expf(2.f * x)); }

// ---------------- mask kernel: mask[b,t] = any(x[b,t,:] != 0) ----------------
__global__ __launch_bounds__(256) void mask_kernel(const float* __restrict__ x,
                                                   float* __restrict__ maskF) {
  int row = blockIdx.x;
  int tid = threadIdx.x;
  const float4* xr = (const float4*)(x + (size_t)row * FF);
  float4 v = xr[tid];
  bool nz = (v.x != 0.f) || (v.y != 0.f) || (v.z != 0.f) || (v.w != 0.f);
  __shared__ int flag;
  if (tid == 0) flag = 0;
  __syncthreads();
  if (__any(nz)) {
    if ((tid & 63) == 0) atomicOr(&flag, 1);
  }
  __syncthreads();
  if (tid == 0) maskF[row] = flag ? 1.f : 0.f;
}

// ---- pack W_h (256x1024 f32, [u][c]) -> whP [1024 cols][256 k] fp8 e4m3 -----
// Scaled by 16 (values land in e4m3's normal range); undone by 0.0625 in rec.
__global__ __launch_bounds__(256) void pack_whP(const float* __restrict__ Wh,
                                                uint8_t* __restrict__ whP) {
  int col = blockIdx.x;   // 0..1023
  int k = threadIdx.x;    // 0..255
  __hip_fp8_e4m3 f(Wh[(size_t)k * GG + col] * 16.f);
  whP[col * 256 + k] = (uint8_t)f.__x;
}

// ---------------- MFMA GEMM: C(f16) = [relu](A @ B + bias) -------------------
// A: M x K (row-major, TA = float or __half), B: K x N (row-major f32)
// tile 128(M) x 64(N), BK=32, 256 threads = 4 waves (2x2 wave grid)
template <typename TA, bool RELU>
__global__ __launch_bounds__(256) void gemm16(const TA* __restrict__ A,
                                              const float* __restrict__ Bm,
                                              const float* __restrict__ bias,
                                              __half* __restrict__ C,
                                              int M, int N, int K) {
  __shared__ _Float16 As[128][40];
  __shared__ _Float16 Bs[64][40];
  int tid = threadIdx.x;
  int lane = tid & 63, w = tid >> 6;
  int wm = w & 1, wn = w >> 1;
  int m0 = blockIdx.x * 128, n0 = blockIdx.y * 64;
  int fr = lane & 15, ks = lane >> 4;

  f32x4 acc[4][2];
#pragma unroll
  for (int i = 0; i < 4; ++i)
#pragma unroll
    for (int j = 0; j < 2; ++j) acc[i][j] = (f32x4){0.f, 0.f, 0.f, 0.f};

  for (int k0 = 0; k0 < K; k0 += 32) {
    {
      int r = tid >> 3, kq = (tid & 7) * 4;
#pragma unroll
      for (int i = 0; i < 4; ++i) {
        int row = r + 32 * i;
        const TA* src = A + (size_t)(m0 + row) * K + k0 + kq;
        if constexpr (sizeof(TA) == 4) {
          float4 v = *reinterpret_cast<const float4*>(src);
          union { uint2 u; _Float16 h[4]; } pk;
          pk.h[0] = (_Float16)v.x; pk.h[1] = (_Float16)v.y;
          pk.h[2] = (_Float16)v.z; pk.h[3] = (_Float16)v.w;
          *reinterpret_cast<uint2*>(&As[row][kq]) = pk.u;
        } else {
          uint2 v = *reinterpret_cast<const uint2*>(src);
          *reinterpret_cast<uint2*>(&As[row][kq]) = v;
        }
      }
      int nn = tid & 63, kb = tid >> 6;
#pragma unroll
      for (int i = 0; i < 8; ++i) {
        int kk = kb + 4 * i;
        Bs[nn][kk] = (_Float16)Bm[(size_t)(k0 + kk) * N + n0 + nn];
      }
    }
    __syncthreads();
    f16x8 af[4], bf[2];
#pragma unroll
    for (int fm = 0; fm < 4; ++fm)
      af[fm] = *reinterpret_cast<const f16x8*>(&As[wm * 64 + fm * 16 + fr][ks * 8]);
#pragma unroll
    for (int fn = 0; fn < 2; ++fn)
      bf[fn] = *reinterpret_cast<const f16x8*>(&Bs[wn * 32 + fn * 16 + fr][ks * 8]);
#pragma unroll
    for (int fm = 0; fm < 4; ++fm)
#pragma unroll
      for (int fn = 0; fn < 2; ++fn)
        acc[fm][fn] = __builtin_amdgcn_mfma_f32_16x16x32_f16(af[fm], bf[fn], acc[fm][fn], 0, 0, 0);
    __syncthreads();
  }
#pragma unroll
  for (int fm = 0; fm < 4; ++fm)
#pragma unroll
    for (int fn = 0; fn < 2; ++fn) {
      int mg0 = m0 + wm * 64 + fm * 16 + ks * 4;
      int ng = n0 + wn * 32 + fn * 16 + fr;
      float bv = bias[ng];
#pragma unroll
      for (int r = 0; r < 4; ++r) {
        float v = acc[fm][fn][r] + bv;
        if constexpr (RELU) v = fmaxf(v, 0.f);
        C[(size_t)(mg0 + r) * N + ng] = __float2half(v);
      }
    }
}

// ---------------- recurrence: fp8 MFMA GEMV, one block per batch -------------
// 1024 threads = 16 waves; empirical arch-VGPR cap 65536/1024 = 64, design
// needs ~52. Wave w owns ALL FOUR gates of u-cols [w*16, w*16+16):
// ct=gate g -> W_h col g*256 + w*16 + fr. After 32 MFMAs the wave's D frags
// are (gi,gf,gg,go) for its own 16 cols -> cell update is wave-local
// (lanes 0..15, c/h in thread regs), no gbuf, ONE barrier per step.
// h (fp8, 256B) ping-pongs between two LDS buffers; read buf p, write p^1.
// W_h fp8 [col][k] (x16 scaled): kt 0..3 in regs (32 VGPR), kt 4..7 in LDS.
__global__ void __launch_bounds__(1024, 1)
lstm_rec(const uint8_t* __restrict__ whP,   // [1024][256] fp8 (x16)
         const __half* __restrict__ zxh,    // [B*T][1024]
         const float* __restrict__ maskF,   // [B*T]
         const float* __restrict__ Wp,      // [256]
         const float* __restrict__ bp,      // [1]
         float* __restrict__ out)           // [B*T]
{
  __shared__ uint2 ldsW2[16 * 1024];                 // 128KB [slot][tid]
  __shared__ __align__(16) uint32_t hpk[2][64];      // 2 x 256B fp8 h (ping-pong)
  __shared__ float red[2][16];                       // per-wave Wp partial sums

  const int b = blockIdx.x;
  const int t = threadIdx.x;
  const int lane = t & 63, w = t >> 6;
  const int fr = lane & 15, q = lane >> 4;

  const uint2* whP2 = (const uint2*)whP;  // uint2 idx = col*32 + kt*4 + q

  // --- preload register B-frags: kt=0..3, ct=gate 0..3 (32 VGPRs) ---
  pk8 bfr[4][4];
#pragma unroll
  for (int kt = 0; kt < 4; ++kt)
#pragma unroll
    for (int ct = 0; ct < 4; ++ct) {
      int col = ct * 256 + w * 16 + fr;
      bfr[kt][ct].u = whP2[col * 32 + kt * 4 + q];
    }
  // --- fill LDS with kt=4..7 (each thread stores exactly what it reads) ---
#pragma unroll
  for (int kt = 4; kt < 8; ++kt)
#pragma unroll
    for (int ct = 0; ct < 4; ++ct) {
      int col = ct * 256 + w * 16 + fr;
      ldsW2[((kt - 4) * 4 + ct) * 1024 + t] = whP2[col * 32 + kt * 4 + q];
    }
  // Pin reg frags live (forbid remat of the global loads inside the loop).
#pragma unroll
  for (int kt = 0; kt < 4; ++kt)
#pragma unroll
    for (int ct = 0; ct < 4; ++ct)
      asm volatile("" : "+v"(bfr[kt][ct].u.x), "+v"(bfr[kt][ct].u.y));

  if (t < 64) hpk[0][t] = 0u;
  float c_state = 0.f, h_state = 0.f;
  float wpv = (lane < 16) ? Wp[w * 16 + lane] : 0.f;
  float bpv = bp[0];
  __syncthreads();

  const __half* zp = zxh + (size_t)b * TT * GG;
  const float* mrow = maskF + b * TT;
  float* outp = out + b * TT;

  int p = 0;
  for (int step = 0; step < TT; ++step) {
    // prefetch cell-phase operands (latency hides under the MFMA phase)
    __half zi{}, zf{}, zg{}, zo{};
    float mval = 0.f;
    if (lane < 16) {
      int u = w * 16 + lane;
      zi = zp[u];
      zf = zp[u + 256];
      zg = zp[u + 512];
      zo = zp[u + 768];
      mval = mrow[step];
    }

    // ---- MFMA phase: this wave's 4 gate-col-tiles, K=256 ----
    const uint2* hp2 = (const uint2*)hpk[p];
    f32x4 d0 = {0.f, 0.f, 0.f, 0.f}, d1 = d0, d2 = d0, d3 = d0;
#pragma unroll
    for (int kt = 0; kt < 8; ++kt) {
      pk8 a;
      a.u = hp2[kt * 4 + q];          // broadcast within 16-lane groups
      pk8 w0, w1, w2, w3;
      if (kt < 4) {
        w0 = bfr[kt][0]; w1 = bfr[kt][1]; w2 = bfr[kt][2]; w3 = bfr[kt][3];
      } else {
        int s = (kt - 4) * 4;
        w0.u = ldsW2[(s + 0) * 1024 + t];
        w1.u = ldsW2[(s + 1) * 1024 + t];
        w2.u = ldsW2[(s + 2) * 1024 + t];
        w3.u = ldsW2[(s + 3) * 1024 + t];
      }
      d0 = __builtin_amdgcn_mfma_f32_16x16x32_fp8_fp8(a.l, w0.l, d0, 0, 0, 0);
      d1 = __builtin_amdgcn_mfma_f32_16x16x32_fp8_fp8(a.l, w1.l, d1, 0, 0, 0);
      d2 = __builtin_amdgcn_mfma_f32_16x16x32_fp8_fp8(a.l, w2.l, d2, 0, 0, 0);
      d3 = __builtin_amdgcn_mfma_f32_16x16x32_fp8_fp8(a.l, w3.l, d3, 0, 0, 0);
    }

    // ---- cell phase: wave-local, lanes 0..15 (rows of D are replicated) ----
    if (lane < 16) {
      float gi = fmaf(d0[0], 0.0625f, __half2float(zi));
      float gf = fmaf(d1[0], 0.0625f, __half2float(zf));
      float gg = fmaf(d2[0], 0.0625f, __half2float(zg));
      float go = fmaf(d3[0], 0.0625f, __half2float(zo));
      float ig = sigmf_(gi);
      float fg = sigmf_(gf);
      float g_ = tanhf_(gg);
      float og = sigmf_(go);
      float cn = fg * c_state + ig * g_;
      float hn = og * tanhf_(cn);
      bool on = (mval > 0.5f);
      c_state = on ? cn : c_state;
      h_state = on ? hn : h_state;
      // h -> fp8 bytes, pack 4 per u32, gather 16B to lane 0, one b128 write
      __hip_fp8_e4m3 f8(h_state);
      uint32_t hb = (uint32_t)f8.__x;
      hb |= __shfl_down(hb, 1) << 8;
      hb |= __shfl_down(hb, 2) << 16;   // lanes 0,4,8,12 now hold packed u32
      uint32_t g1 = __shfl(hb, 4);
      uint32_t g2 = __shfl(hb, 8);
      uint32_t g3 = __shfl(hb, 12);
      if (lane == 0) {
        uint4 hv = {hb, g1, g2, g3};
        ((uint4*)hpk[p ^ 1])[w] = hv;
      }
      // output projection partial: sum over this wave's 16 cols
      float pp = h_state * wpv;
      pp += __shfl_down(pp, 8);
      pp += __shfl_down(pp, 4);
      pp += __shfl_down(pp, 2);
      pp += __shfl_down(pp, 1);
      if (lane == 0) red[p][w] = pp;
    }
    __syncthreads();
    if (t == 0) {
      float s = bpv;
#pragma unroll
      for (int i = 0; i < 16; ++i) s += red[p][i];
      outp[step] = 1.f / (1.f + __expf(-s));
    }
    p ^= 1;
    zp += GG;
  }
}

extern "C" void kernel_launch(void* const* d_in, const int* in_sizes, int n_in,
                              void* d_out, int out_size, void* d_ws, size_t ws_size,
                              hipStream_t stream) {
  const float* x = (const float*)d_in[0];
  const float* Wfc = (const float*)d_in[1];
  const float* bfc = (const float*)d_in[2];
  const float* Wx = (const float*)d_in[3];
  const float* Wh = (const float*)d_in[4];
  const float* blstm = (const float*)d_in[5];
  const float* Wp = (const float*)d_in[6];
  const float* bp = (const float*)d_in[7];
  float* out = (float*)d_out;

  char* ws = (char*)d_ws;
  float* maskF = (float*)(ws);                                   // 128 KB
  __half* zh = (__half*)(ws + 131072);                           // 16.78 MB
  __half* zxh = (__half*)(ws + 131072 + 16777216);               // 67.1 MB
  uint8_t* whP = (uint8_t*)(ws + 131072 + 16777216 + 67108864);  // 256 KB

  mask_kernel<<<BB * TT, 256, 0, stream>>>(x, maskF);
  pack_whP<<<GG, 256, 0, stream>>>(Wh, whP);
  gemm16<float, true><<<dim3((BB * TT) / 128, UU / 64), 256, 0, stream>>>(
      x, Wfc, bfc, zh, BB * TT, UU, FF);
  gemm16<__half, false><<<dim3((BB * TT) / 128, GG / 64), 256, 0, stream>>>(
      zh, Wx, blstm, zxh, BB * TT, GG, UU);
  lstm_rec<<<BB, 1024, 0, stream>>>(whP, zxh, maskF, Wp, bp, out);
}

// Round 8
// 1053.603 us; speedup vs baseline: 1.1332x; 1.1332x over previous
//
#include <hip/hip_runtime.h>
#include <hip/hip_fp16.h>
#include <hip/hip_fp8.h>
#include <cstdint>

// B=64, T=512, F=1024, U=256, G=4U=1024
#define BB 64
#define TT 512
#define FF 1024
#define UU 256
#define GG 1024

typedef _Float16 f16x8 __attribute__((ext_vector_type(8)));
typedef float f32x4 __attribute__((ext_vector_type(4)));

typedef union { uint2 u; long long l; } pk8;   // 8 fp8 = one MFMA operand (2 VGPRs)

__device__ __forceinline__ float sigmf_(float x) { return 1.f / (1.f + __expf(-x)); }
__device__ __forceinline__ float tanhf_(float x) { return 1.f - 2.f / (1.f + __expf(2.f * x)); }

// ---------------- mask kernel: mask[b,t] = any(x[b,t,:] != 0) ----------------
__global__ __launch_bounds__(256) void mask_kernel(const float* __restrict__ x,
                                                   float* __restrict__ maskF) {
  int row = blockIdx.x;
  int tid = threadIdx.x;
  const float4* xr = (const float4*)(x + (size_t)row * FF);
  float4 v = xr[tid];
  bool nz = (v.x != 0.f) || (v.y != 0.f) || (v.z != 0.f) || (v.w != 0.f);
  __shared__ int flag;
  if (tid == 0) flag = 0;
  __syncthreads();
  if (__any(nz)) {
    if ((tid & 63) == 0) atomicOr(&flag, 1);
  }
  __syncthreads();
  if (tid == 0) maskF[row] = flag ? 1.f : 0.f;
}

// ---- pack W_h (256x1024 f32, [u][c]) -> whP [1024 cols][256 k] fp8 e4m3 -----
// Scaled by 16 (values land in e4m3's normal range); undone by 0.0625 in rec.
__global__ __launch_bounds__(256) void pack_whP(const float* __restrict__ Wh,
                                                uint8_t* __restrict__ whP) {
  int col = blockIdx.x;   // 0..1023
  int k = threadIdx.x;    // 0..255
  __hip_fp8_e4m3 f(Wh[(size_t)k * GG + col] * 16.f);
  whP[col * 256 + k] = (uint8_t)f.__x;
}

// ---------------- MFMA GEMM: C(f16) = [relu](A @ B + bias) -------------------
// A: M x K (row-major, TA = float or __half), B: K x N (row-major f32)
// tile 128(M) x 64(N), BK=32, 256 threads = 4 waves (2x2 wave grid)
template <typename TA, bool RELU>
__global__ __launch_bounds__(256) void gemm16(const TA* __restrict__ A,
                                              const float* __restrict__ Bm,
                                              const float* __restrict__ bias,
                                              __half* __restrict__ C,
                                              int M, int N, int K) {
  __shared__ _Float16 As[128][40];
  __shared__ _Float16 Bs[64][40];
  int tid = threadIdx.x;
  int lane = tid & 63, w = tid >> 6;
  int wm = w & 1, wn = w >> 1;
  int m0 = blockIdx.x * 128, n0 = blockIdx.y * 64;
  int fr = lane & 15, ks = lane >> 4;

  f32x4 acc[4][2];
#pragma unroll
  for (int i = 0; i < 4; ++i)
#pragma unroll
    for (int j = 0; j < 2; ++j) acc[i][j] = (f32x4){0.f, 0.f, 0.f, 0.f};

  for (int k0 = 0; k0 < K; k0 += 32) {
    {
      int r = tid >> 3, kq = (tid & 7) * 4;
#pragma unroll
      for (int i = 0; i < 4; ++i) {
        int row = r + 32 * i;
        const TA* src = A + (size_t)(m0 + row) * K + k0 + kq;
        if constexpr (sizeof(TA) == 4) {
          float4 v = *reinterpret_cast<const float4*>(src);
          union { uint2 u; _Float16 h[4]; } pk;
          pk.h[0] = (_Float16)v.x; pk.h[1] = (_Float16)v.y;
          pk.h[2] = (_Float16)v.z; pk.h[3] = (_Float16)v.w;
          *reinterpret_cast<uint2*>(&As[row][kq]) = pk.u;
        } else {
          uint2 v = *reinterpret_cast<const uint2*>(src);
          *reinterpret_cast<uint2*>(&As[row][kq]) = v;
        }
      }
      int nn = tid & 63, kb = tid >> 6;
#pragma unroll
      for (int i = 0; i < 8; ++i) {
        int kk = kb + 4 * i;
        Bs[nn][kk] = (_Float16)Bm[(size_t)(k0 + kk) * N + n0 + nn];
      }
    }
    __syncthreads();
    f16x8 af[4], bf[2];
#pragma unroll
    for (int fm = 0; fm < 4; ++fm)
      af[fm] = *reinterpret_cast<const f16x8*>(&As[wm * 64 + fm * 16 + fr][ks * 8]);
#pragma unroll
    for (int fn = 0; fn < 2; ++fn)
      bf[fn] = *reinterpret_cast<const f16x8*>(&Bs[wn * 32 + fn * 16 + fr][ks * 8]);
#pragma unroll
    for (int fm = 0; fm < 4; ++fm)
#pragma unroll
      for (int fn = 0; fn < 2; ++fn)
        acc[fm][fn] = __builtin_amdgcn_mfma_f32_16x16x32_f16(af[fm], bf[fn], acc[fm][fn], 0, 0, 0);
    __syncthreads();
  }
#pragma unroll
  for (int fm = 0; fm < 4; ++fm)
#pragma unroll
    for (int fn = 0; fn < 2; ++fn) {
      int mg0 = m0 + wm * 64 + fm * 16 + ks * 4;
      int ng = n0 + wn * 32 + fn * 16 + fr;
      float bv = bias[ng];
#pragma unroll
      for (int r = 0; r < 4; ++r) {
        float v = acc[fm][fn][r] + bv;
        if constexpr (RELU) v = fmaxf(v, 0.f);
        C[(size_t)(mg0 + r) * N + ng] = __float2half(v);
      }
    }
}

// ---------------- recurrence: fp8 MFMA GEMV, one block per batch -------------
// 1024 threads = 16 waves; arch-VGPR cap 65536/1024 = 64, design needs ~56.
// Wave w owns ALL FOUR gates of u-cols [w*16, w*16+16). One barrier per step.
// zx/mask loads are software-pipelined one step ahead (zxh streams from
// L3/HBM, ~500-900cy latency; pipelining hides it under the MFMA phase).
// Cell phase runs in all 64 lanes (D rows are replicated so every lane holds
// its column's 4 gate values) - no exec-mask churn; writes stay lane-guarded.
__global__ void __launch_bounds__(1024, 1)
lstm_rec(const uint8_t* __restrict__ whP,   // [1024][256] fp8 (x16)
         const __half* __restrict__ zxh,    // [B*T][1024]
         const float* __restrict__ maskF,   // [B*T]
         const float* __restrict__ Wp,      // [256]
         const float* __restrict__ bp,      // [1]
         float* __restrict__ out)           // [B*T]
{
  __shared__ uint2 ldsW2[16 * 1024];                 // 128KB [slot][tid]
  __shared__ __align__(16) uint32_t hpk[2][64];      // 2 x 256B fp8 h (ping-pong)
  __shared__ float red[2][16];                       // per-wave Wp partial sums

  const int b = blockIdx.x;
  const int t = threadIdx.x;
  const int lane = t & 63, w = t >> 6;
  const int fr = lane & 15, q = lane >> 4;

  const uint2* whP2 = (const uint2*)whP;  // uint2 idx = col*32 + kt*4 + q

  // --- preload register B-frags: kt=0..3, ct=gate 0..3 (32 VGPRs) ---
  pk8 bfr[4][4];
#pragma unroll
  for (int kt = 0; kt < 4; ++kt)
#pragma unroll
    for (int ct = 0; ct < 4; ++ct) {
      int col = ct * 256 + w * 16 + fr;
      bfr[kt][ct].u = whP2[col * 32 + kt * 4 + q];
    }
  // --- fill LDS with kt=4..7 (each thread stores exactly what it reads) ---
#pragma unroll
  for (int kt = 4; kt < 8; ++kt)
#pragma unroll
    for (int ct = 0; ct < 4; ++ct) {
      int col = ct * 256 + w * 16 + fr;
      ldsW2[((kt - 4) * 4 + ct) * 1024 + t] = whP2[col * 32 + kt * 4 + q];
    }
  // Pin reg frags live (forbid remat of the global loads inside the loop).
#pragma unroll
  for (int kt = 0; kt < 4; ++kt)
#pragma unroll
    for (int ct = 0; ct < 4; ++ct)
      asm volatile("" : "+v"(bfr[kt][ct].u.x), "+v"(bfr[kt][ct].u.y));

  if (t < 64) hpk[0][t] = 0u;
  float c_state = 0.f, h_state = 0.f;
  float wpv = (lane < 16) ? Wp[w * 16 + fr] : 0.f;
  float bpv = bp[0];
  __syncthreads();

  const __half* zp = zxh + (size_t)b * TT * GG;
  const float* mrow = maskF + b * TT;
  float* outp = out + b * TT;
  const int u = w * 16 + fr;

  // --- software pipeline: preload step 0's zx/mask ---
  __half zi_c = zp[u], zf_c = zp[u + 256], zg_c = zp[u + 512], zo_c = zp[u + 768];
  float mval_c = mrow[0];

  int p = 0;
  for (int step = 0; step < TT; ++step) {
    // issue next step's loads now; consumed after the MFMA phase next iter
    const __half* zq = zp + ((step + 1 < TT) ? GG : 0);
    int sn = (step + 1 < TT) ? step + 1 : step;
    __half zi_n = zq[u], zf_n = zq[u + 256], zg_n = zq[u + 512], zo_n = zq[u + 768];
    float mval_n = mrow[sn];

    // ---- MFMA phase: this wave's 4 gate-col-tiles, K=256 ----
    const uint2* hp2 = (const uint2*)hpk[p];
    f32x4 d0 = {0.f, 0.f, 0.f, 0.f}, d1 = d0, d2 = d0, d3 = d0;
#pragma unroll
    for (int kt = 0; kt < 8; ++kt) {
      pk8 a;
      a.u = hp2[kt * 4 + q];          // broadcast within 16-lane groups
      pk8 w0, w1, w2, w3;
      if (kt < 4) {
        w0 = bfr[kt][0]; w1 = bfr[kt][1]; w2 = bfr[kt][2]; w3 = bfr[kt][3];
      } else {
        int s = (kt - 4) * 4;
        w0.u = ldsW2[(s + 0) * 1024 + t];
        w1.u = ldsW2[(s + 1) * 1024 + t];
        w2.u = ldsW2[(s + 2) * 1024 + t];
        w3.u = ldsW2[(s + 3) * 1024 + t];
      }
      d0 = __builtin_amdgcn_mfma_f32_16x16x32_fp8_fp8(a.l, w0.l, d0, 0, 0, 0);
      d1 = __builtin_amdgcn_mfma_f32_16x16x32_fp8_fp8(a.l, w1.l, d1, 0, 0, 0);
      d2 = __builtin_amdgcn_mfma_f32_16x16x32_fp8_fp8(a.l, w2.l, d2, 0, 0, 0);
      d3 = __builtin_amdgcn_mfma_f32_16x16x32_fp8_fp8(a.l, w3.l, d3, 0, 0, 0);
    }

    // ---- cell phase: all 64 lanes (D rows replicated; lane's col = fr) ----
    {
      float gi = fmaf(d0[0], 0.0625f, __half2float(zi_c));
      float gf = fmaf(d1[0], 0.0625f, __half2float(zf_c));
      float gg = fmaf(d2[0], 0.0625f, __half2float(zg_c));
      float go = fmaf(d3[0], 0.0625f, __half2float(zo_c));
      float ig = sigmf_(gi);
      float fg = sigmf_(gf);
      float g_ = tanhf_(gg);
      float og = sigmf_(go);
      float cn = fg * c_state + ig * g_;
      float hn = og * tanhf_(cn);
      bool on = (mval_c > 0.5f);
      c_state = on ? cn : c_state;
      h_state = on ? hn : h_state;
      // h -> fp8 bytes, pack 4 per u32, gather 16B to lane 0, one b128 write
      __hip_fp8_e4m3 f8(h_state);
      uint32_t hb = (uint32_t)f8.__x;
      hb |= __shfl_down(hb, 1) << 8;
      hb |= __shfl_down(hb, 2) << 16;   // lanes 0,4,8,12 hold packed u32
      uint32_t g1 = __shfl(hb, 4);
      uint32_t g2 = __shfl(hb, 8);
      uint32_t g3 = __shfl(hb, 12);
      if (lane == 0) {
        uint4 hv = {hb, g1, g2, g3};
        ((uint4*)hpk[p ^ 1])[w] = hv;
      }
      // output projection partial: sum over this wave's 16 cols (lanes 0-15)
      float pp = h_state * wpv;
      pp += __shfl_down(pp, 8);
      pp += __shfl_down(pp, 4);
      pp += __shfl_down(pp, 2);
      pp += __shfl_down(pp, 1);
      if (lane == 0) red[p][w] = pp;
    }
    __syncthreads();
    if (w == (step & 15) && lane == 0) {  // rotate the output wave
      float s = bpv;
#pragma unroll
      for (int i = 0; i < 16; ++i) s += red[p][i];
      outp[step] = 1.f / (1.f + __expf(-s));
    }
    p ^= 1;
    zp += GG;
    zi_c = zi_n; zf_c = zf_n; zg_c = zg_n; zo_c = zo_n; mval_c = mval_n;
  }
}

extern "C" void kernel_launch(void* const* d_in, const int* in_sizes, int n_in,
                              void* d_out, int out_size, void* d_ws, size_t ws_size,
                              hipStream_t stream) {
  const float* x = (const float*)d_in[0];
  const float* Wfc = (const float*)d_in[1];
  const float* bfc = (const float*)d_in[2];
  const float* Wx = (const float*)d_in[3];
  const float* Wh = (const float*)d_in[4];
  const float* blstm = (const float*)d_in[5];
  const float* Wp = (const float*)d_in[6];
  const float* bp = (const float*)d_in[7];
  float* out = (float*)d_out;

  char* ws = (char*)d_ws;
  float* maskF = (float*)(ws);                                   // 128 KB
  __half* zh = (__half*)(ws + 131072);                           // 16.78 MB
  __half* zxh = (__half*)(ws + 131072 + 16777216);               // 67.1 MB
  uint8_t* whP = (uint8_t*)(ws + 131072 + 16777216 + 67108864);  // 256 KB

  mask_kernel<<<BB * TT, 256, 0, stream>>>(x, maskF);
  pack_whP<<<GG, 256, 0, stream>>>(Wh, whP);
  gemm16<float, true><<<dim3((BB * TT) / 128, UU / 64), 256, 0, stream>>>(
      x, Wfc, bfc, zh, BB * TT, UU, FF);
  gemm16<__half, false><<<dim3((BB * TT) / 128, GG / 64), 256, 0, stream>>>(
      zh, Wx, blstm, zxh, BB * TT, GG, UU);
  lstm_rec<<<BB, 1024, 0, stream>>>(whP, zxh, maskF, Wp, bp, out);
}

// Round 9
// 915.252 us; speedup vs baseline: 1.3045x; 1.1512x over previous
//
#include <hip/hip_runtime.h>
#include <hip/hip_fp16.h>
#include <hip/hip_fp8.h>
#include <cstdint>

// B=64, T=512, F=1024, U=256, G=4U=1024
#define BB 64
#define TT 512
#define FF 1024
#define UU 256
#define GG 1024

typedef _Float16 f16x8 __attribute__((ext_vector_type(8)));
typedef float f32x4 __attribute__((ext_vector_type(4)));

typedef union { uint2 u; long long l; } pk8;   // 8 fp8 = one MFMA operand (2 VGPRs)

__device__ __forceinline__ float sigmf_(float x) { return 1.f / (1.f + __expf(-x)); }
__device__ __forceinline__ float tanhf_(float x) { return 1.f - 2.f / (1.f + __expf(2.f * x)); }

// ---------------- mask kernel: mask[b,t] = any(x[b,t,:] != 0) ----------------
__global__ __launch_bounds__(256) void mask_kernel(const float* __restrict__ x,
                                                   float* __restrict__ maskF) {
  int row = blockIdx.x;
  int tid = threadIdx.x;
  const float4* xr = (const float4*)(x + (size_t)row * FF);
  float4 v = xr[tid];
  bool nz = (v.x != 0.f) || (v.y != 0.f) || (v.z != 0.f) || (v.w != 0.f);
  __shared__ int flag;
  if (tid == 0) flag = 0;
  __syncthreads();
  if (__any(nz)) {
    if ((tid & 63) == 0) atomicOr(&flag, 1);
  }
  __syncthreads();
  if (tid == 0) maskF[row] = flag ? 1.f : 0.f;
}

// ---- pack W_h (256x1024 f32, [u][c]) -> whP [1024 cols][256 k] fp8 e4m3 -----
// Scaled by 16 (values land in e4m3's normal range); undone by 0.0625 in rec.
__global__ __launch_bounds__(256) void pack_whP(const float* __restrict__ Wh,
                                                uint8_t* __restrict__ whP) {
  int col = blockIdx.x;   // 0..1023
  int k = threadIdx.x;    // 0..255
  __hip_fp8_e4m3 f(Wh[(size_t)k * GG + col] * 16.f);
  whP[col * 256 + k] = (uint8_t)f.__x;
}

// ---------------- MFMA GEMM: C(f16) = [relu](A @ B + bias) -------------------
// A: M x K (row-major, TA = float or __half), B: K x N (row-major f32)
// tile 128(M) x 64(N), BK=32, 256 threads = 4 waves (2x2 wave grid)
template <typename TA, bool RELU>
__global__ __launch_bounds__(256) void gemm16(const TA* __restrict__ A,
                                              const float* __restrict__ Bm,
                                              const float* __restrict__ bias,
                                              __half* __restrict__ C,
                                              int M, int N, int K) {
  __shared__ _Float16 As[128][40];
  __shared__ _Float16 Bs[64][40];
  int tid = threadIdx.x;
  int lane = tid & 63, w = tid >> 6;
  int wm = w & 1, wn = w >> 1;
  int m0 = blockIdx.x * 128, n0 = blockIdx.y * 64;
  int fr = lane & 15, ks = lane >> 4;

  f32x4 acc[4][2];
#pragma unroll
  for (int i = 0; i < 4; ++i)
#pragma unroll
    for (int j = 0; j < 2; ++j) acc[i][j] = (f32x4){0.f, 0.f, 0.f, 0.f};

  for (int k0 = 0; k0 < K; k0 += 32) {
    {
      int r = tid >> 3, kq = (tid & 7) * 4;
#pragma unroll
      for (int i = 0; i < 4; ++i) {
        int row = r + 32 * i;
        const TA* src = A + (size_t)(m0 + row) * K + k0 + kq;
        if constexpr (sizeof(TA) == 4) {
          float4 v = *reinterpret_cast<const float4*>(src);
          union { uint2 u; _Float16 h[4]; } pk;
          pk.h[0] = (_Float16)v.x; pk.h[1] = (_Float16)v.y;
          pk.h[2] = (_Float16)v.z; pk.h[3] = (_Float16)v.w;
          *reinterpret_cast<uint2*>(&As[row][kq]) = pk.u;
        } else {
          uint2 v = *reinterpret_cast<const uint2*>(src);
          *reinterpret_cast<uint2*>(&As[row][kq]) = v;
        }
      }
      int nn = tid & 63, kb = tid >> 6;
#pragma unroll
      for (int i = 0; i < 8; ++i) {
        int kk = kb + 4 * i;
        Bs[nn][kk] = (_Float16)Bm[(size_t)(k0 + kk) * N + n0 + nn];
      }
    }
    __syncthreads();
    f16x8 af[4], bf[2];
#pragma unroll
    for (int fm = 0; fm < 4; ++fm)
      af[fm] = *reinterpret_cast<const f16x8*>(&As[wm * 64 + fm * 16 + fr][ks * 8]);
#pragma unroll
    for (int fn = 0; fn < 2; ++fn)
      bf[fn] = *reinterpret_cast<const f16x8*>(&Bs[wn * 32 + fn * 16 + fr][ks * 8]);
#pragma unroll
    for (int fm = 0; fm < 4; ++fm)
#pragma unroll
      for (int fn = 0; fn < 2; ++fn)
        acc[fm][fn] = __builtin_amdgcn_mfma_f32_16x16x32_f16(af[fm], bf[fn], acc[fm][fn], 0, 0, 0);
    __syncthreads();
  }
#pragma unroll
  for (int fm = 0; fm < 4; ++fm)
#pragma unroll
    for (int fn = 0; fn < 2; ++fn) {
      int mg0 = m0 + wm * 64 + fm * 16 + ks * 4;
      int ng = n0 + wn * 32 + fn * 16 + fr;
      float bv = bias[ng];
#pragma unroll
      for (int r = 0; r < 4; ++r) {
        float v = acc[fm][fn][r] + bv;
        if constexpr (RELU) v = fmaxf(v, 0.f);
        C[(size_t)(mg0 + r) * N + ng] = __float2half(v);
      }
    }
}

// ---------------- recurrence: fp8 MFMA GEMV, one block per batch -------------
// 1024 threads = 16 waves; arch-VGPR cap 65536/1024 = 64, design needs ~50.
// Wave w owns ALL FOUR gates of u-cols [w*16, w*16+16). One barrier per step.
// Critical-path diet (R9): h-repack is a single ds_write_b8 per col (no
// shuffles); output projection is exported as per-col f16 partial products
// (pp = h*wp), with the global store DEFERRED to the next step's top so the
// pre-barrier vmcnt drain never waits on it. A separate proj_kernel reduces.
__global__ void __launch_bounds__(1024, 1)
lstm_rec(const uint8_t* __restrict__ whP,   // [1024][256] fp8 (x16)
         const __half* __restrict__ zxh,    // [B*T][1024]
         const float* __restrict__ maskF,   // [B*T]
         const float* __restrict__ Wp,      // [256]
         __half* __restrict__ ppG)          // [B*T][256] f16: h*wp per col
{
  __shared__ uint2 ldsW2[16 * 1024];                 // 128KB [slot][tid]
  __shared__ __align__(16) uint8_t hpk[2][256];      // fp8 h (ping-pong)

  const int b = blockIdx.x;
  const int t = threadIdx.x;
  const int lane = t & 63, w = t >> 6;
  const int fr = lane & 15, q = lane >> 4;

  const uint2* whP2 = (const uint2*)whP;  // uint2 idx = col*32 + kt*4 + q

  // --- preload register B-frags: kt=0..3, ct=gate 0..3 (32 VGPRs) ---
  pk8 bfr[4][4];
#pragma unroll
  for (int kt = 0; kt < 4; ++kt)
#pragma unroll
    for (int ct = 0; ct < 4; ++ct) {
      int col = ct * 256 + w * 16 + fr;
      bfr[kt][ct].u = whP2[col * 32 + kt * 4 + q];
    }
  // --- fill LDS with kt=4..7 (each thread stores exactly what it reads) ---
#pragma unroll
  for (int kt = 4; kt < 8; ++kt)
#pragma unroll
    for (int ct = 0; ct < 4; ++ct) {
      int col = ct * 256 + w * 16 + fr;
      ldsW2[((kt - 4) * 4 + ct) * 1024 + t] = whP2[col * 32 + kt * 4 + q];
    }
  // Pin reg frags live (forbid remat of the global loads inside the loop).
#pragma unroll
  for (int kt = 0; kt < 4; ++kt)
#pragma unroll
    for (int ct = 0; ct < 4; ++ct)
      asm volatile("" : "+v"(bfr[kt][ct].u.x), "+v"(bfr[kt][ct].u.y));

  if (t < 64) ((uint32_t*)hpk[0])[t] = 0u;
  float c_state = 0.f, h_state = 0.f;
  float wpv = Wp[w * 16 + fr];
  __syncthreads();

  const __half* zp = zxh + (size_t)b * TT * GG;
  const float* mrow = maskF + b * TT;
  __half* ppp = ppG + (size_t)b * TT * UU;
  const int u = w * 16 + fr;

  // --- software pipeline: preload step 0's zx/mask ---
  __half zi_c = zp[u], zf_c = zp[u + 256], zg_c = zp[u + 512], zo_c = zp[u + 768];
  float mval_c = mrow[0];
  __half pp_prev = __float2half(0.f);

  int p = 0;
  for (int step = 0; step < TT; ++step) {
    // deferred store of previous step's pp (drains during the MFMA phase)
    if (step > 0 && q == 0) ppp[(size_t)(step - 1) * UU + u] = pp_prev;

    // issue next step's zx/mask loads; consumed next iteration
    const __half* zq = zp + ((step + 1 < TT) ? GG : 0);
    int sn = (step + 1 < TT) ? step + 1 : step;
    __half zi_n = zq[u], zf_n = zq[u + 256], zg_n = zq[u + 512], zo_n = zq[u + 768];
    float mval_n = mrow[sn];

    // ---- MFMA phase: this wave's 4 gate-col-tiles, K=256 ----
    const uint2* hp2 = (const uint2*)hpk[p];
    f32x4 d0 = {0.f, 0.f, 0.f, 0.f}, d1 = d0, d2 = d0, d3 = d0;
#pragma unroll
    for (int kt = 0; kt < 8; ++kt) {
      pk8 a;
      a.u = hp2[kt * 4 + q];          // broadcast within 16-lane groups
      pk8 w0, w1, w2, w3;
      if (kt < 4) {
        w0 = bfr[kt][0]; w1 = bfr[kt][1]; w2 = bfr[kt][2]; w3 = bfr[kt][3];
      } else {
        int s = (kt - 4) * 4;
        w0.u = ldsW2[(s + 0) * 1024 + t];
        w1.u = ldsW2[(s + 1) * 1024 + t];
        w2.u = ldsW2[(s + 2) * 1024 + t];
        w3.u = ldsW2[(s + 3) * 1024 + t];
      }
      d0 = __builtin_amdgcn_mfma_f32_16x16x32_fp8_fp8(a.l, w0.l, d0, 0, 0, 0);
      d1 = __builtin_amdgcn_mfma_f32_16x16x32_fp8_fp8(a.l, w1.l, d1, 0, 0, 0);
      d2 = __builtin_amdgcn_mfma_f32_16x16x32_fp8_fp8(a.l, w2.l, d2, 0, 0, 0);
      d3 = __builtin_amdgcn_mfma_f32_16x16x32_fp8_fp8(a.l, w3.l, d3, 0, 0, 0);
    }

    // ---- cell phase: all 64 lanes (D rows replicated; lane's col = fr) ----
    {
      float gi = fmaf(d0[0], 0.0625f, __half2float(zi_c));
      float gf = fmaf(d1[0], 0.0625f, __half2float(zf_c));
      float gg = fmaf(d2[0], 0.0625f, __half2float(zg_c));
      float go = fmaf(d3[0], 0.0625f, __half2float(zo_c));
      float ig = sigmf_(gi);
      float fg = sigmf_(gf);
      float g_ = tanhf_(gg);
      float og = sigmf_(go);
      float cn = fg * c_state + ig * g_;
      float hn = og * tanhf_(cn);
      bool on = (mval_c > 0.5f);
      c_state = on ? cn : c_state;
      h_state = on ? hn : h_state;
      // h -> fp8: ONE byte write per col (lanes q==0), no shuffles
      __hip_fp8_e4m3 f8(h_state);
      if (q == 0) hpk[p ^ 1][u] = (uint8_t)f8.__x;
      pp_prev = __float2half(h_state * wpv);
    }
    __syncthreads();
    p ^= 1;
    zp += GG;
    zi_c = zi_n; zf_c = zf_n; zg_c = zg_n; zo_c = zo_n; mval_c = mval_n;
  }
  if (q == 0) ppp[(size_t)(TT - 1) * UU + u] = pp_prev;
}

// --------- projection: out[row] = sigmoid(sum_u ppG[row][u] + bp) ------------
__global__ __launch_bounds__(256) void proj_kernel(const __half* __restrict__ ppG,
                                                   const float* __restrict__ bp,
                                                   float* __restrict__ out) {
  int row = blockIdx.x * 4 + (threadIdx.x >> 6);
  int lane = threadIdx.x & 63;
  const ushort4* pr = (const ushort4*)(ppG + (size_t)row * UU);
  ushort4 v = pr[lane];
  __half2 a = *reinterpret_cast<__half2*>(&v.x);
  __half2 c = *reinterpret_cast<__half2*>(&v.z);
  float2 af = __half22float2(a), cf = __half22float2(c);
  float s = af.x + af.y + cf.x + cf.y;
#pragma unroll
  for (int off = 32; off > 0; off >>= 1) s += __shfl_down(s, off);
  if (lane == 0) out[row] = 1.f / (1.f + __expf(-(s + bp[0])));
}

extern "C" void kernel_launch(void* const* d_in, const int* in_sizes, int n_in,
                              void* d_out, int out_size, void* d_ws, size_t ws_size,
                              hipStream_t stream) {
  const float* x = (const float*)d_in[0];
  const float* Wfc = (const float*)d_in[1];
  const float* bfc = (const float*)d_in[2];
  const float* Wx = (const float*)d_in[3];
  const float* Wh = (const float*)d_in[4];
  const float* blstm = (const float*)d_in[5];
  const float* Wp = (const float*)d_in[6];
  const float* bp = (const float*)d_in[7];
  float* out = (float*)d_out;

  char* ws = (char*)d_ws;
  float* maskF = (float*)(ws);                                   // 128 KB
  __half* zh = (__half*)(ws + 131072);                           // 16.78 MB
  __half* zxh = (__half*)(ws + 131072 + 16777216);               // 67.1 MB
  uint8_t* whP = (uint8_t*)(ws + 131072 + 16777216 + 67108864);  // 256 KB
  __half* ppG = zh;  // zh is dead after gemm_zx; exact size match (16.78 MB)

  mask_kernel<<<BB * TT, 256, 0, stream>>>(x, maskF);
  pack_whP<<<GG, 256, 0, stream>>>(Wh, whP);
  gemm16<float, true><<<dim3((BB * TT) / 128, UU / 64), 256, 0, stream>>>(
      x, Wfc, bfc, zh, BB * TT, UU, FF);
  gemm16<__half, false><<<dim3((BB * TT) / 128, GG / 64), 256, 0, stream>>>(
      zh, Wx, blstm, zxh, BB * TT, GG, UU);
  lstm_rec<<<BB, 1024, 0, stream>>>(whP, zxh, maskF, Wp, ppG);
  proj_kernel<<<(BB * TT) / 4, 256, 0, stream>>>(ppG, bp, out);
}

// Round 10
// 842.980 us; speedup vs baseline: 1.4163x; 1.0857x over previous
//
#include <hip/hip_runtime.h>
#include <hip/hip_fp16.h>
#include <hip/hip_fp8.h>
#include <cstdint>

// B=64, T=512, F=1024, U=256, G=4U=1024
#define BB 64
#define TT 512
#define FF 1024
#define UU 256
#define GG 1024

typedef _Float16 f16x8 __attribute__((ext_vector_type(8)));
typedef float f32x4 __attribute__((ext_vector_type(4)));

typedef union { uint2 u; long long l; } pk8;   // 8 fp8 = one MFMA operand (2 VGPRs)

__device__ __forceinline__ float sigmf_(float x) { return 1.f / (1.f + __expf(-x)); }
__device__ __forceinline__ float tanhf_(float x) { return 1.f - 2.f / (1.f + __expf(2.f * x)); }

// ---------------- mask kernel: mask[b,t] = any(x[b,t,:] != 0) ----------------
__global__ __launch_bounds__(256) void mask_kernel(const float* __restrict__ x,
                                                   float* __restrict__ maskF) {
  int row = blockIdx.x;
  int tid = threadIdx.x;
  const float4* xr = (const float4*)(x + (size_t)row * FF);
  float4 v = xr[tid];
  bool nz = (v.x != 0.f) || (v.y != 0.f) || (v.z != 0.f) || (v.w != 0.f);
  __shared__ int flag;
  if (tid == 0) flag = 0;
  __syncthreads();
  if (__any(nz)) {
    if ((tid & 63) == 0) atomicOr(&flag, 1);
  }
  __syncthreads();
  if (tid == 0) maskF[row] = flag ? 1.f : 0.f;
}

// ---- pack W_h (256x1024 f32, [u][c]) -> whP [1024 cols][256 k] fp8 e4m3 -----
// Scaled by 16 (values land in e4m3's normal range); undone by 0.0625 in rec.
__global__ __launch_bounds__(256) void pack_whP(const float* __restrict__ Wh,
                                                uint8_t* __restrict__ whP) {
  int col = blockIdx.x;   // 0..1023
  int k = threadIdx.x;    // 0..255
  __hip_fp8_e4m3 f(Wh[(size_t)k * GG + col] * 16.f);
  whP[col * 256 + k] = (uint8_t)f.__x;
}

// ---------------- MFMA GEMM: C(f16) = [relu](A @ B + bias) -------------------
// A: M x K (row-major, TA = float or __half), B: K x N (row-major f32)
// tile 128(M) x 64(N), BK=32, 256 threads = 4 waves (2x2 wave grid)
template <typename TA, bool RELU>
__global__ __launch_bounds__(256) void gemm16(const TA* __restrict__ A,
                                              const float* __restrict__ Bm,
                                              const float* __restrict__ bias,
                                              __half* __restrict__ C,
                                              int M, int N, int K) {
  __shared__ _Float16 As[128][40];
  __shared__ _Float16 Bs[64][40];
  int tid = threadIdx.x;
  int lane = tid & 63, w = tid >> 6;
  int wm = w & 1, wn = w >> 1;
  int m0 = blockIdx.x * 128, n0 = blockIdx.y * 64;
  int fr = lane & 15, ks = lane >> 4;

  f32x4 acc[4][2];
#pragma unroll
  for (int i = 0; i < 4; ++i)
#pragma unroll
    for (int j = 0; j < 2; ++j) acc[i][j] = (f32x4){0.f, 0.f, 0.f, 0.f};

  for (int k0 = 0; k0 < K; k0 += 32) {
    {
      int r = tid >> 3, kq = (tid & 7) * 4;
#pragma unroll
      for (int i = 0; i < 4; ++i) {
        int row = r + 32 * i;
        const TA* src = A + (size_t)(m0 + row) * K + k0 + kq;
        if constexpr (sizeof(TA) == 4) {
          float4 v = *reinterpret_cast<const float4*>(src);
          union { uint2 u; _Float16 h[4]; } pk;
          pk.h[0] = (_Float16)v.x; pk.h[1] = (_Float16)v.y;
          pk.h[2] = (_Float16)v.z; pk.h[3] = (_Float16)v.w;
          *reinterpret_cast<uint2*>(&As[row][kq]) = pk.u;
        } else {
          uint2 v = *reinterpret_cast<const uint2*>(src);
          *reinterpret_cast<uint2*>(&As[row][kq]) = v;
        }
      }
      int nn = tid & 63, kb = tid >> 6;
#pragma unroll
      for (int i = 0; i < 8; ++i) {
        int kk = kb + 4 * i;
        Bs[nn][kk] = (_Float16)Bm[(size_t)(k0 + kk) * N + n0 + nn];
      }
    }
    __syncthreads();
    f16x8 af[4], bf[2];
#pragma unroll
    for (int fm = 0; fm < 4; ++fm)
      af[fm] = *reinterpret_cast<const f16x8*>(&As[wm * 64 + fm * 16 + fr][ks * 8]);
#pragma unroll
    for (int fn = 0; fn < 2; ++fn)
      bf[fn] = *reinterpret_cast<const f16x8*>(&Bs[wn * 32 + fn * 16 + fr][ks * 8]);
#pragma unroll
    for (int fm = 0; fm < 4; ++fm)
#pragma unroll
      for (int fn = 0; fn < 2; ++fn)
        acc[fm][fn] = __builtin_amdgcn_mfma_f32_16x16x32_f16(af[fm], bf[fn], acc[fm][fn], 0, 0, 0);
    __syncthreads();
  }
#pragma unroll
  for (int fm = 0; fm < 4; ++fm)
#pragma unroll
    for (int fn = 0; fn < 2; ++fn) {
      int mg0 = m0 + wm * 64 + fm * 16 + ks * 4;
      int ng = n0 + wn * 32 + fn * 16 + fr;
      float bv = bias[ng];
#pragma unroll
      for (int r = 0; r < 4; ++r) {
        float v = acc[fm][fn][r] + bv;
        if constexpr (RELU) v = fmaxf(v, 0.f);
        C[(size_t)(mg0 + r) * N + ng] = __float2half(v);
      }
    }
}

// ---------------- recurrence: fp8 MFMA GEMV, one block per batch -------------
// 1024 threads = 16 waves = 4 waves/EU. Per-CU VRF = 512KB => per-wave
// unified budget at 4 waves/EU is 128 regs (NOT 64 = the compiler's default
// 8-wave/EU plan). launch_bounds(1024,1) [min 1 wave/EU] + waves_per_eu(4,4)
// request exactly that occupancy. ALL of W_h (fp8, 256KB) lives in registers:
// 64 VGPR/thread of weights + ~20 working set + acc. LDS holds only the
// 2x256B fp8 h ping-pong. Per step: barrier -> 8x ds_read_b64 (h) ->
// 32 all-register MFMAs -> cell -> 1 ds_write_b8 -> barrier.
__attribute__((amdgpu_waves_per_eu(4, 4)))
__global__ void __launch_bounds__(1024, 1)
lstm_rec(const uint8_t* __restrict__ whP,   // [1024][256] fp8 (x16)
         const __half* __restrict__ zxh,    // [B*T][1024]
         const float* __restrict__ maskF,   // [B*T]
         const float* __restrict__ Wp,      // [256]
         __half* __restrict__ ppG)          // [B*T][256] f16: h*wp per col
{
  __shared__ __align__(16) uint8_t hpk[2][256];      // fp8 h (ping-pong)

  const int b = blockIdx.x;
  const int t = threadIdx.x;
  const int lane = t & 63, w = t >> 6;
  const int fr = lane & 15, q = lane >> 4;

  const uint2* whP2 = (const uint2*)whP;  // uint2 idx = col*32 + kt*4 + q

  // --- preload ALL weight B-frags: kt=0..7, ct=gate 0..3 (64 VGPRs) ---
  pk8 bfr[8][4];
#pragma unroll
  for (int kt = 0; kt < 8; ++kt)
#pragma unroll
    for (int ct = 0; ct < 4; ++ct) {
      int col = ct * 256 + w * 16 + fr;
      bfr[kt][ct].u = whP2[col * 32 + kt * 4 + q];
    }
  // Pin frags live (forbid remat of the global loads inside the loop).
#pragma unroll
  for (int kt = 0; kt < 8; ++kt)
#pragma unroll
    for (int ct = 0; ct < 4; ++ct)
      asm volatile("" : "+v"(bfr[kt][ct].u.x), "+v"(bfr[kt][ct].u.y));

  if (t < 64) ((uint32_t*)hpk[0])[t] = 0u;
  float c_state = 0.f, h_state = 0.f;
  float wpv = Wp[w * 16 + fr];
  __syncthreads();

  const __half* zp = zxh + (size_t)b * TT * GG;
  const float* mrow = maskF + b * TT;
  __half* ppp = ppG + (size_t)b * TT * UU;
  const int u = w * 16 + fr;

  // --- software pipeline: preload step 0's zx/mask ---
  __half zi_c = zp[u], zf_c = zp[u + 256], zg_c = zp[u + 512], zo_c = zp[u + 768];
  float mval_c = mrow[0];
  __half pp_prev = __float2half(0.f);

  int p = 0;
  for (int step = 0; step < TT; ++step) {
    // deferred store of previous step's pp (drains during the MFMA phase)
    if (step > 0 && q == 0) ppp[(size_t)(step - 1) * UU + u] = pp_prev;

    // issue next step's zx/mask loads; consumed next iteration
    const __half* zq = zp + ((step + 1 < TT) ? GG : 0);
    int sn = (step + 1 < TT) ? step + 1 : step;
    __half zi_n = zq[u], zf_n = zq[u + 256], zg_n = zq[u + 512], zo_n = zq[u + 768];
    float mval_n = mrow[sn];

    // ---- MFMA phase: this wave's 4 gate-col-tiles, K=256, all-register ----
    const uint2* hp2 = (const uint2*)hpk[p];
    f32x4 d0 = {0.f, 0.f, 0.f, 0.f}, d1 = d0, d2 = d0, d3 = d0;
#pragma unroll
    for (int kt = 0; kt < 8; ++kt) {
      pk8 a;
      a.u = hp2[kt * 4 + q];          // broadcast within 16-lane groups
      d0 = __builtin_amdgcn_mfma_f32_16x16x32_fp8_fp8(a.l, bfr[kt][0].l, d0, 0, 0, 0);
      d1 = __builtin_amdgcn_mfma_f32_16x16x32_fp8_fp8(a.l, bfr[kt][1].l, d1, 0, 0, 0);
      d2 = __builtin_amdgcn_mfma_f32_16x16x32_fp8_fp8(a.l, bfr[kt][2].l, d2, 0, 0, 0);
      d3 = __builtin_amdgcn_mfma_f32_16x16x32_fp8_fp8(a.l, bfr[kt][3].l, d3, 0, 0, 0);
    }

    // ---- cell phase: all 64 lanes (D rows replicated; lane's col = fr) ----
    {
      float gi = fmaf(d0[0], 0.0625f, __half2float(zi_c));
      float gf = fmaf(d1[0], 0.0625f, __half2float(zf_c));
      float gg = fmaf(d2[0], 0.0625f, __half2float(zg_c));
      float go = fmaf(d3[0], 0.0625f, __half2float(zo_c));
      float ig = sigmf_(gi);
      float fg = sigmf_(gf);
      float g_ = tanhf_(gg);
      float og = sigmf_(go);
      float cn = fg * c_state + ig * g_;
      float hn = og * tanhf_(cn);
      bool on = (mval_c > 0.5f);
      c_state = on ? cn : c_state;
      h_state = on ? hn : h_state;
      // h -> fp8: ONE byte write per col (lanes q==0), no shuffles
      __hip_fp8_e4m3 f8(h_state);
      if (q == 0) hpk[p ^ 1][u] = (uint8_t)f8.__x;
      pp_prev = __float2half(h_state * wpv);
    }
    __syncthreads();
    p ^= 1;
    zp += GG;
    zi_c = zi_n; zf_c = zf_n; zg_c = zg_n; zo_c = zo_n; mval_c = mval_n;
  }
  if (q == 0) ppp[(size_t)(TT - 1) * UU + u] = pp_prev;
}

// --------- projection: out[row] = sigmoid(sum_u ppG[row][u] + bp) ------------
__global__ __launch_bounds__(256) void proj_kernel(const __half* __restrict__ ppG,
                                                   const float* __restrict__ bp,
                                                   float* __restrict__ out) {
  int row = blockIdx.x * 4 + (threadIdx.x >> 6);
  int lane = threadIdx.x & 63;
  const ushort4* pr = (const ushort4*)(ppG + (size_t)row * UU);
  ushort4 v = pr[lane];
  __half2 a = *reinterpret_cast<__half2*>(&v.x);
  __half2 c = *reinterpret_cast<__half2*>(&v.z);
  float2 af = __half22float2(a), cf = __half22float2(c);
  float s = af.x + af.y + cf.x + cf.y;
#pragma unroll
  for (int off = 32; off > 0; off >>= 1) s += __shfl_down(s, off);
  if (lane == 0) out[row] = 1.f / (1.f + __expf(-(s + bp[0])));
}

extern "C" void kernel_launch(void* const* d_in, const int* in_sizes, int n_in,
                              void* d_out, int out_size, void* d_ws, size_t ws_size,
                              hipStream_t stream) {
  const float* x = (const float*)d_in[0];
  const float* Wfc = (const float*)d_in[1];
  const float* bfc = (const float*)d_in[2];
  const float* Wx = (const float*)d_in[3];
  const float* Wh = (const float*)d_in[4];
  const float* blstm = (const float*)d_in[5];
  const float* Wp = (const float*)d_in[6];
  const float* bp = (const float*)d_in[7];
  float* out = (float*)d_out;

  char* ws = (char*)d_ws;
  float* maskF = (float*)(ws);                                   // 128 KB
  __half* zh = (__half*)(ws + 131072);                           // 16.78 MB
  __half* zxh = (__half*)(ws + 131072 + 16777216);               // 67.1 MB
  uint8_t* whP = (uint8_t*)(ws + 131072 + 16777216 + 67108864);  // 256 KB
  __half* ppG = zh;  // zh is dead after gemm_zx; exact size match (16.78 MB)

  mask_kernel<<<BB * TT, 256, 0, stream>>>(x, maskF);
  pack_whP<<<GG, 256, 0, stream>>>(Wh, whP);
  gemm16<float, true><<<dim3((BB * TT) / 128, UU / 64), 256, 0, stream>>>(
      x, Wfc, bfc, zh, BB * TT, UU, FF);
  gemm16<__half, false><<<dim3((BB * TT) / 128, GG / 64), 256, 0, stream>>>(
      zh, Wx, blstm, zxh, BB * TT, GG, UU);
  lstm_rec<<<BB, 1024, 0, stream>>>(whP, zxh, maskF, Wp, ppG);
  proj_kernel<<<(BB * TT) / 4, 256, 0, stream>>>(ppG, bp, out);
}

// Round 11
// 737.863 us; speedup vs baseline: 1.6181x; 1.1425x over previous
//
#include <hip/hip_runtime.h>
#include <hip/hip_fp16.h>
#include <hip/hip_fp8.h>
#include <cstdint>

// B=64, T=512, F=1024, U=256, G=4U=1024
#define BB 64
#define TT 512
#define FF 1024
#define UU 256
#define GG 1024

typedef _Float16 f16x8 __attribute__((ext_vector_type(8)));
typedef float f32x4 __attribute__((ext_vector_type(4)));
typedef int i32x8 __attribute__((ext_vector_type(8)));

typedef union { uint4 u4[2]; i32x8 v; } pk32;  // 32 fp8 = one K=128 MFMA operand

__device__ __forceinline__ float sigmf_(float x) { return 1.f / (1.f + __expf(-x)); }
__device__ __forceinline__ float tanhf_(float x) { return 1.f - 2.f / (1.f + __expf(2.f * x)); }

// ---------------- mask kernel: mask[b,t] = any(x[b,t,:] != 0) ----------------
__global__ __launch_bounds__(256) void mask_kernel(const float* __restrict__ x,
                                                   float* __restrict__ maskF) {
  int row = blockIdx.x;
  int tid = threadIdx.x;
  const float4* xr = (const float4*)(x + (size_t)row * FF);
  float4 v = xr[tid];
  bool nz = (v.x != 0.f) || (v.y != 0.f) || (v.z != 0.f) || (v.w != 0.f);
  __shared__ int flag;
  if (tid == 0) flag = 0;
  __syncthreads();
  if (__any(nz)) {
    if ((tid & 63) == 0) atomicOr(&flag, 1);
  }
  __syncthreads();
  if (tid == 0) maskF[row] = flag ? 1.f : 0.f;
}

// ---- pack W_h (256x1024 f32, [u][c]) -> whP [1024 cols][256 k] fp8 e4m3 -----
// Scaled by 16 (values land in e4m3's normal range); undone by 0.0625 in rec.
__global__ __launch_bounds__(256) void pack_whP(const float* __restrict__ Wh,
                                                uint8_t* __restrict__ whP) {
  int col = blockIdx.x;   // 0..1023
  int k = threadIdx.x;    // 0..255
  __hip_fp8_e4m3 f(Wh[(size_t)k * GG + col] * 16.f);
  whP[col * 256 + k] = (uint8_t)f.__x;
}

// ---------------- MFMA GEMM: C(f16) = [relu](A @ B + bias) -------------------
// A: M x K (row-major, TA = float or __half), B: K x N (row-major f32)
// tile 128(M) x 64(N), BK=32, 256 threads = 4 waves (2x2 wave grid)
template <typename TA, bool RELU>
__global__ __launch_bounds__(256) void gemm16(const TA* __restrict__ A,
                                              const float* __restrict__ Bm,
                                              const float* __restrict__ bias,
                                              __half* __restrict__ C,
                                              int M, int N, int K) {
  __shared__ _Float16 As[128][40];
  __shared__ _Float16 Bs[64][40];
  int tid = threadIdx.x;
  int lane = tid & 63, w = tid >> 6;
  int wm = w & 1, wn = w >> 1;
  int m0 = blockIdx.x * 128, n0 = blockIdx.y * 64;
  int fr = lane & 15, ks = lane >> 4;

  f32x4 acc[4][2];
#pragma unroll
  for (int i = 0; i < 4; ++i)
#pragma unroll
    for (int j = 0; j < 2; ++j) acc[i][j] = (f32x4){0.f, 0.f, 0.f, 0.f};

  for (int k0 = 0; k0 < K; k0 += 32) {
    {
      int r = tid >> 3, kq = (tid & 7) * 4;
#pragma unroll
      for (int i = 0; i < 4; ++i) {
        int row = r + 32 * i;
        const TA* src = A + (size_t)(m0 + row) * K + k0 + kq;
        if constexpr (sizeof(TA) == 4) {
          float4 v = *reinterpret_cast<const float4*>(src);
          union { uint2 u; _Float16 h[4]; } pk;
          pk.h[0] = (_Float16)v.x; pk.h[1] = (_Float16)v.y;
          pk.h[2] = (_Float16)v.z; pk.h[3] = (_Float16)v.w;
          *reinterpret_cast<uint2*>(&As[row][kq]) = pk.u;
        } else {
          uint2 v = *reinterpret_cast<const uint2*>(src);
          *reinterpret_cast<uint2*>(&As[row][kq]) = v;
        }
      }
      int nn = tid & 63, kb = tid >> 6;
#pragma unroll
      for (int i = 0; i < 8; ++i) {
        int kk = kb + 4 * i;
        Bs[nn][kk] = (_Float16)Bm[(size_t)(k0 + kk) * N + n0 + nn];
      }
    }
    __syncthreads();
    f16x8 af[4], bf[2];
#pragma unroll
    for (int fm = 0; fm < 4; ++fm)
      af[fm] = *reinterpret_cast<const f16x8*>(&As[wm * 64 + fm * 16 + fr][ks * 8]);
#pragma unroll
    for (int fn = 0; fn < 2; ++fn)
      bf[fn] = *reinterpret_cast<const f16x8*>(&Bs[wn * 32 + fn * 16 + fr][ks * 8]);
#pragma unroll
    for (int fm = 0; fm < 4; ++fm)
#pragma unroll
      for (int fn = 0; fn < 2; ++fn)
        acc[fm][fn] = __builtin_amdgcn_mfma_f32_16x16x32_f16(af[fm], bf[fn], acc[fm][fn], 0, 0, 0);
    __syncthreads();
  }
#pragma unroll
  for (int fm = 0; fm < 4; ++fm)
#pragma unroll
    for (int fn = 0; fn < 2; ++fn) {
      int mg0 = m0 + wm * 64 + fm * 16 + ks * 4;
      int ng = n0 + wn * 32 + fn * 16 + fr;
      float bv = bias[ng];
#pragma unroll
      for (int r = 0; r < 4; ++r) {
        float v = acc[fm][fn][r] + bv;
        if constexpr (RELU) v = fmaxf(v, 0.f);
        C[(size_t)(mg0 + r) * N + ng] = __float2half(v);
      }
    }
}

// ---------------- recurrence: MX fp8 K=128 MFMA GEMV, one block/batch --------
// 1024 threads = 16 waves. R10 structure (all-register weights, 512B LDS,
// one barrier, deferred pp export) with the inner loop swapped to
// mfma_scale_f32_16x16x128_f8f6f4 (FMT 0 = fp8 e4m3, unit E8M0 scales):
// 8 MFMAs/wave/step instead of 32, at ~2x the FLOP rate -> MFMA floor
// drops 2510 -> ~1100 cy/step. Math identical to R10 modulo summation order.
__attribute__((amdgpu_waves_per_eu(4, 4)))
__global__ void __launch_bounds__(1024, 1)
lstm_rec(const uint8_t* __restrict__ whP,   // [1024][256] fp8 (x16)
         const __half* __restrict__ zxh,    // [B*T][1024]
         const float* __restrict__ maskF,   // [B*T]
         const float* __restrict__ Wp,      // [256]
         __half* __restrict__ ppG)          // [B*T][256] f16: h*wp per col
{
  __shared__ __align__(16) uint8_t hpk[2][256];      // fp8 h (ping-pong)

  const int b = blockIdx.x;
  const int t = threadIdx.x;
  const int lane = t & 63, w = t >> 6;
  const int fr = lane & 15, q = lane >> 4;
  const int SC1 = 0x7F7F7F7F;  // E8M0 exponent 127 = x1.0 scale, all bytes

  const uint4* whP4 = (const uint4*)whP;  // uint4 idx = col*16 + kt*8 + q*2

  // --- preload ALL weight B-frags: kt=0..1 (K=128 each), ct=gate 0..3 ---
  // per frag: 32 fp8 = 2 uint4 = 8 regs; total 4ct*2kt*8 = 64 regs (AGPR-able)
  pk32 bfr[2][4];
#pragma unroll
  for (int kt = 0; kt < 2; ++kt)
#pragma unroll
    for (int ct = 0; ct < 4; ++ct) {
      int col = ct * 256 + w * 16 + fr;
      bfr[kt][ct].u4[0] = whP4[col * 16 + kt * 8 + q * 2];
      bfr[kt][ct].u4[1] = whP4[col * 16 + kt * 8 + q * 2 + 1];
    }
  // Pin frags live (forbid remat of the global loads inside the loop).
#pragma unroll
  for (int kt = 0; kt < 2; ++kt)
#pragma unroll
    for (int ct = 0; ct < 4; ++ct) {
      asm volatile("" : "+v"(bfr[kt][ct].u4[0].x), "+v"(bfr[kt][ct].u4[0].y),
                        "+v"(bfr[kt][ct].u4[0].z), "+v"(bfr[kt][ct].u4[0].w));
      asm volatile("" : "+v"(bfr[kt][ct].u4[1].x), "+v"(bfr[kt][ct].u4[1].y),
                        "+v"(bfr[kt][ct].u4[1].z), "+v"(bfr[kt][ct].u4[1].w));
    }

  if (t < 64) ((uint32_t*)hpk[0])[t] = 0u;
  float c_state = 0.f, h_state = 0.f;
  float wpv = Wp[w * 16 + fr];
  __syncthreads();

  const __half* zp = zxh + (size_t)b * TT * GG;
  const float* mrow = maskF + b * TT;
  __half* ppp = ppG + (size_t)b * TT * UU;
  const int u = w * 16 + fr;

  // --- software pipeline: preload step 0's zx/mask ---
  __half zi_c = zp[u], zf_c = zp[u + 256], zg_c = zp[u + 512], zo_c = zp[u + 768];
  float mval_c = mrow[0];
  __half pp_prev = __float2half(0.f);

  int p = 0;
  for (int step = 0; step < TT; ++step) {
    // deferred store of previous step's pp (drains during the MFMA phase)
    if (step > 0 && q == 0) ppp[(size_t)(step - 1) * UU + u] = pp_prev;

    // issue next step's zx/mask loads; consumed next iteration
    const __half* zq = zp + ((step + 1 < TT) ? GG : 0);
    int sn = (step + 1 < TT) ? step + 1 : step;
    __half zi_n = zq[u], zf_n = zq[u + 256], zg_n = zq[u + 512], zo_n = zq[u + 768];
    float mval_n = mrow[sn];

    // ---- MFMA phase: 4 gate-col-tiles x 2 K-halves, all-register B ----
    const uint4* hp4 = (const uint4*)hpk[p];  // 16 uint4; kt*8 + q*2 (+1)
    f32x4 d0 = {0.f, 0.f, 0.f, 0.f}, d1 = d0, d2 = d0, d3 = d0;
#pragma unroll
    for (int kt = 0; kt < 2; ++kt) {
      pk32 a;
      a.u4[0] = hp4[kt * 8 + q * 2];      // broadcast within 16-lane groups
      a.u4[1] = hp4[kt * 8 + q * 2 + 1];
      d0 = __builtin_amdgcn_mfma_scale_f32_16x16x128_f8f6f4(
          a.v, bfr[kt][0].v, d0, 0, 0, 0, SC1, 0, SC1);
      d1 = __builtin_amdgcn_mfma_scale_f32_16x16x128_f8f6f4(
          a.v, bfr[kt][1].v, d1, 0, 0, 0, SC1, 0, SC1);
      d2 = __builtin_amdgcn_mfma_scale_f32_16x16x128_f8f6f4(
          a.v, bfr[kt][2].v, d2, 0, 0, 0, SC1, 0, SC1);
      d3 = __builtin_amdgcn_mfma_scale_f32_16x16x128_f8f6f4(
          a.v, bfr[kt][3].v, d3, 0, 0, 0, SC1, 0, SC1);
    }

    // ---- cell phase: all 64 lanes (D rows replicated; lane's col = fr) ----
    {
      float gi = fmaf(d0[0], 0.0625f, __half2float(zi_c));
      float gf = fmaf(d1[0], 0.0625f, __half2float(zf_c));
      float gg = fmaf(d2[0], 0.0625f, __half2float(zg_c));
      float go = fmaf(d3[0], 0.0625f, __half2float(zo_c));
      float ig = sigmf_(gi);
      float fg = sigmf_(gf);
      float g_ = tanhf_(gg);
      float og = sigmf_(go);
      float cn = fg * c_state + ig * g_;
      float hn = og * tanhf_(cn);
      bool on = (mval_c > 0.5f);
      c_state = on ? cn : c_state;
      h_state = on ? hn : h_state;
      // h -> fp8: ONE byte write per col (lanes q==0), no shuffles
      __hip_fp8_e4m3 f8(h_state);
      if (q == 0) hpk[p ^ 1][u] = (uint8_t)f8.__x;
      pp_prev = __float2half(h_state * wpv);
    }
    __syncthreads();
    p ^= 1;
    zp += GG;
    zi_c = zi_n; zf_c = zf_n; zg_c = zg_n; zo_c = zo_n; mval_c = mval_n;
  }
  if (q == 0) ppp[(size_t)(TT - 1) * UU + u] = pp_prev;
}

// --------- projection: out[row] = sigmoid(sum_u ppG[row][u] + bp) ------------
__global__ __launch_bounds__(256) void proj_kernel(const __half* __restrict__ ppG,
                                                   const float* __restrict__ bp,
                                                   float* __restrict__ out) {
  int row = blockIdx.x * 4 + (threadIdx.x >> 6);
  int lane = threadIdx.x & 63;
  const ushort4* pr = (const ushort4*)(ppG + (size_t)row * UU);
  ushort4 v = pr[lane];
  __half2 a = *reinterpret_cast<__half2*>(&v.x);
  __half2 c = *reinterpret_cast<__half2*>(&v.z);
  float2 af = __half22float2(a), cf = __half22float2(c);
  float s = af.x + af.y + cf.x + cf.y;
#pragma unroll
  for (int off = 32; off > 0; off >>= 1) s += __shfl_down(s, off);
  if (lane == 0) out[row] = 1.f / (1.f + __expf(-(s + bp[0])));
}

extern "C" void kernel_launch(void* const* d_in, const int* in_sizes, int n_in,
                              void* d_out, int out_size, void* d_ws, size_t ws_size,
                              hipStream_t stream) {
  const float* x = (const float*)d_in[0];
  const float* Wfc = (const float*)d_in[1];
  const float* bfc = (const float*)d_in[2];
  const float* Wx = (const float*)d_in[3];
  const float* Wh = (const float*)d_in[4];
  const float* blstm = (const float*)d_in[5];
  const float* Wp = (const float*)d_in[6];
  const float* bp = (const float*)d_in[7];
  float* out = (float*)d_out;

  char* ws = (char*)d_ws;
  float* maskF = (float*)(ws);                                   // 128 KB
  __half* zh = (__half*)(ws + 131072);                           // 16.78 MB
  __half* zxh = (__half*)(ws + 131072 + 16777216);               // 67.1 MB
  uint8_t* whP = (uint8_t*)(ws + 131072 + 16777216 + 67108864);  // 256 KB
  __half* ppG = zh;  // zh is dead after gemm_zx; exact size match (16.78 MB)

  mask_kernel<<<BB * TT, 256, 0, stream>>>(x, maskF);
  pack_whP<<<GG, 256, 0, stream>>>(Wh, whP);
  gemm16<float, true><<<dim3((BB * TT) / 128, UU / 64), 256, 0, stream>>>(
      x, Wfc, bfc, zh, BB * TT, UU, FF);
  gemm16<__half, false><<<dim3((BB * TT) / 128, GG / 64), 256, 0, stream>>>(
      zh, Wx, blstm, zxh, BB * TT, GG, UU);
  lstm_rec<<<BB, 1024, 0, stream>>>(whP, zxh, maskF, Wp, ppG);
  proj_kernel<<<(BB * TT) / 4, 256, 0, stream>>>(ppG, bp, out);
}